// Round 1
// baseline (480.636 us; speedup 1.0000x reference)
//
#include <hip/hip_runtime.h>
#include <hip/hip_bf16.h>
#include <math.h>

#define NTOK   16384
#define NEXP   64
#define HID    4096
#define KSEL   8

// d_out element offsets (f32 elements; int outputs stored as float values)
#define O_LOGITS 0u
#define O_PROBS  1048576u
#define O_TIDX   1179648u
#define O_GROUP  1310720u
#define O_IDX    1310784u
#define O_TPE    1441856u
#define O_LB     1441920u
#define O_ZL     1441921u

// ws byte offsets
#define W_COUNTS  0u          // 64 int
#define W_PROBSUM 256u        // 64 float
#define W_LSQ     512u        // 1 double
#define W_OFFS    1024u       // 64 int (exclusive expert offsets)
#define W_FLAT    4096u       // 131072 int (flat topk expert ids)
#define W_PART    (1u<<20)    // nsplit * 1048576 doubles (partials; slot 0 = reduced logits)
#define PART_STRIDE 1048576ull

// ---------------------------------------------------------------------------
// K0: zero the atomically-accumulated scratch (must happen every call)
__global__ void k_zero(int* counts, float* probsum, double* lsq) {
  int t = threadIdx.x;
  if (t < 64) { counts[t] = 0; probsum[t] = 0.0f; }
  if (t == 0) lsq[0] = 0.0;
}

// ---------------------------------------------------------------------------
// K1: router GEMM, f64 accumulation. Block: 64 rows x 64 experts, split-K.
// 128 threads; thread = 4 rows x 8 experts.
__global__ __launch_bounds__(128) void k_gemm(const float* __restrict__ x,
                                              const float* __restrict__ w,
                                              double* __restrict__ part,
                                              int ksz) {
  __shared__ float  xs[64][33];   // pad 33: conflict-free strided row reads
  __shared__ double wl[32][68];   // pad 68: 16B-aligned 8-expert reads
  const int t0  = blockIdx.x * 64;
  const int k0  = blockIdx.y * ksz;
  const int tid = threadIdx.x;
  const int eg  = tid & 7;    // expert group (8 experts each)
  const int rg  = tid >> 3;   // row group (4 rows each), 0..15

  double acc[4][8];
#pragma unroll
  for (int i = 0; i < 4; ++i)
#pragma unroll
    for (int j = 0; j < 8; ++j) acc[i][j] = 0.0;

  for (int kk = 0; kk < ksz; kk += 32) {
    const int kb = k0 + kk;
    // stage x tile: 64 rows x 32 cols (f32)
#pragma unroll
    for (int i = tid; i < 2048; i += 128) {
      int row = i >> 5, col = i & 31;
      xs[row][col] = x[(size_t)(t0 + row) * HID + kb + col];
    }
    // stage W tile transposed as f64: wl[hh][e]
#pragma unroll
    for (int i = tid; i < 2048; i += 128) {
      int e = i & 63, hh = i >> 6;
      wl[hh][e] = (double)w[(size_t)e * HID + kb + hh];
    }
    __syncthreads();
#pragma unroll 4
    for (int hh = 0; hh < 32; ++hh) {
      double wv[8];
#pragma unroll
      for (int j = 0; j < 8; ++j) wv[j] = wl[hh][eg * 8 + j];
#pragma unroll
      for (int i = 0; i < 4; ++i) {
        double xv = (double)xs[rg * 4 + i][hh];
#pragma unroll
        for (int j = 0; j < 8; ++j) acc[i][j] = fma(xv, wv[j], acc[i][j]);
      }
    }
    __syncthreads();
  }
  double* p = part + (size_t)blockIdx.y * PART_STRIDE;
#pragma unroll
  for (int i = 0; i < 4; ++i) {
    size_t base = (size_t)(t0 + rg * 4 + i) * NEXP + (size_t)eg * 8;
#pragma unroll
    for (int j = 0; j < 8; ++j) p[base + j] = acc[i][j];
  }
}

// ---------------------------------------------------------------------------
// K1b: reduce split-K partials into slot 0 (f64) and write f32 logits out.
__global__ void k_reduce(double* __restrict__ part, float* __restrict__ out_logits,
                         int nsplit) {
  unsigned i = blockIdx.x * 256u + threadIdx.x;  // grid 4096 x 256 = 1048576
  double v = part[i];
  for (int s = 1; s < nsplit; ++s) v += part[(size_t)s * PART_STRIDE + i];
  part[i] = v;
  out_logits[i] = (float)v;
}

// ---------------------------------------------------------------------------
// K2: per-row top-k (stable, f64 clipped keys), topk softmax, histogram,
//     full softmax column-sums (for lb_loss), logsumexp^2 sum (for z-loss).
__global__ __launch_bounds__(256) void k_rowwise(const double* __restrict__ lg,
                                                 float* __restrict__ out,
                                                 int* __restrict__ counts_g,
                                                 float* __restrict__ probsum_g,
                                                 double* __restrict__ lsq_g,
                                                 int* __restrict__ flat) {
  __shared__ int   hist[64];
  __shared__ float ps[4][64];
  const int tid  = threadIdx.x;
  const int lane = tid & 63;
  const int wv   = tid >> 6;
  const unsigned t = blockIdx.x * 256u + tid;  // row, grid 64 x 256 = 16384
  if (tid < 64) hist[tid] = 0;
  __syncthreads();

  const double* lr = lg + (size_t)t * NEXP;

  // pass 1: stable top-8 insertion on clipped f64 keys + raw max
  double val[8]; int idx[8];
#pragma unroll
  for (int j = 0; j < 8; ++j) { val[j] = -1.0e300; idx[j] = 0; }
  double rawmax = -1.0e300;
  for (int e = 0; e < 64; ++e) {
    double v = lr[e];
    rawmax = fmax(rawmax, v);
    double c = fmin(fmax(v, -2.0), 2.0);
    int id = e;
#pragma unroll
    for (int j = 0; j < 8; ++j) {           // strict > : equal keys keep lower index first
      bool sw = c > val[j];
      double tv = sw ? val[j] : c; int ti = sw ? idx[j] : id;
      val[j] = sw ? c : val[j];    idx[j] = sw ? id : idx[j];
      c = tv; id = ti;
    }
  }

  // top-8 softmax (f32 is plenty for the 2% threshold)
  float m = (float)val[0];
  float pe[8], sum = 0.0f;
#pragma unroll
  for (int j = 0; j < 8; ++j) { pe[j] = expf((float)val[j] - m); sum += pe[j]; }
  float inv = 1.0f / sum;
#pragma unroll
  for (int j = 0; j < 8; ++j) {
    out[O_PROBS + (size_t)t * 8 + j] = pe[j] * inv;
    out[O_TIDX  + (size_t)t * 8 + j] = (float)idx[j];
    flat[(size_t)t * 8 + j] = idx[j];
    atomicAdd(&hist[idx[j]], 1);
  }

  // pass 2: full softmax denominator
  float fm = (float)rawmax;
  float se = 0.0f;
  for (int e = 0; e < 64; ++e) se += expf((float)lr[e] - fm);
  float invse = 1.0f / se;

  // pass 3: per-expert prob, wave-reduced across 64 rows, into per-wave LDS slots
  for (int e = 0; e < 64; ++e) {
    float p = expf((float)lr[e] - fm) * invse;
    for (int o = 32; o > 0; o >>= 1) p += __shfl_down(p, o);
    if (lane == 0) ps[wv][e] = p;
  }

  // z-loss partial
  float lse = fm + logf(se);
  float l2 = lse * lse;
  for (int o = 32; o > 0; o >>= 1) l2 += __shfl_down(l2, o);
  if (lane == 0) atomicAdd(lsq_g, (double)l2);

  __syncthreads();
  if (tid < 64) {
    atomicAdd(&counts_g[tid], hist[tid]);
    float g = ps[0][tid] + ps[1][tid] + ps[2][tid] + ps[3][tid];
    atomicAdd(&probsum_g[tid], g);
  }
}

// ---------------------------------------------------------------------------
// K3: cumsum, expert offsets, lb_loss, z-loss finalize. 1 block x 64 threads.
__global__ void k_final(const int* __restrict__ counts, const float* __restrict__ probsum,
                        const double* __restrict__ lsq, float* __restrict__ out,
                        int* __restrict__ offs) {
  __shared__ int c[64];
  int e = threadIdx.x;
  c[e] = counts[e];
  __syncthreads();
  int incl = 0;
  for (int i = 0; i <= e; ++i) incl += c[i];
  out[O_TPE + e]   = (float)c[e];
  out[O_GROUP + e] = (float)incl;
  offs[e] = incl - c[e];
  float term = ((float)c[e] / 131072.0f) * (probsum[e] / 16384.0f) * 64.0f;
  for (int o = 32; o > 0; o >>= 1) term += __shfl_down(term, o);
  if (e == 0) {
    out[O_LB] = term;
    out[O_ZL] = (float)(lsq[0] / 16384.0);
  }
}

// ---------------------------------------------------------------------------
// K4: stable counting-sort scatter (= stable argsort of flat expert ids).
// One block per expert; ordered stream compaction, 8 elems/thread/chunk.
__global__ __launch_bounds__(256) void k_dispatch(const int* __restrict__ flat,
                                                  const int* __restrict__ offs,
                                                  float* __restrict__ out) {
  __shared__ int wcs[4];
  const int e    = blockIdx.x;
  const int tid  = threadIdx.x;
  const int lane = tid & 63;
  const int wv   = tid >> 6;
  int base = offs[e];
  for (int c0 = 0; c0 < NTOK * KSEL; c0 += 2048) {
    const int j0 = c0 + tid * 8;
    const int4* f4 = reinterpret_cast<const int4*>(flat + j0);
    int4 a = f4[0], b = f4[1];
    int v[8] = {a.x, a.y, a.z, a.w, b.x, b.y, b.z, b.w};
    int mcnt = 0;
#pragma unroll
    for (int k = 0; k < 8; ++k) mcnt += (v[k] == e) ? 1 : 0;
    // inclusive wave scan of mcnt
    int sc = mcnt;
#pragma unroll
    for (int o = 1; o < 64; o <<= 1) {
      int n = __shfl_up(sc, o);
      if (lane >= o) sc += n;
    }
    int excl = sc - mcnt;
    if (lane == 63) wcs[wv] = sc;  // wave total
    __syncthreads();
    int woff = 0, tot = 0;
#pragma unroll
    for (int i = 0; i < 4; ++i) { int ci = wcs[i]; woff += (i < wv) ? ci : 0; tot += ci; }
    int pos = base + woff + excl;
#pragma unroll
    for (int k = 0; k < 8; ++k) {
      if (v[k] == e) { out[O_IDX + pos] = (float)(j0 + k); pos++; }
    }
    base += tot;
    __syncthreads();
  }
}

// ---------------------------------------------------------------------------
extern "C" void kernel_launch(void* const* d_in, const int* in_sizes, int n_in,
                              void* d_out, int out_size, void* d_ws, size_t ws_size,
                              hipStream_t stream) {
  (void)in_sizes; (void)n_in; (void)out_size;
  const float* x  = (const float*)d_in[0];
  const float* Wm = (const float*)d_in[1];
  float* out = (float*)d_out;
  char*  ws  = (char*)d_ws;

  int*    counts  = (int*)(ws + W_COUNTS);
  float*  probsum = (float*)(ws + W_PROBSUM);
  double* lsq     = (double*)(ws + W_LSQ);
  int*    offs    = (int*)(ws + W_OFFS);
  int*    flat    = (int*)(ws + W_FLAT);
  double* part    = (double*)(ws + W_PART);

  // adaptive split-K by available scratch
  int nsplit = 1;
  if (ws_size >= (size_t)W_PART + 4ull * PART_STRIDE * 8ull) nsplit = 4;
  else if (ws_size >= (size_t)W_PART + 2ull * PART_STRIDE * 8ull) nsplit = 2;
  const int ksz = HID / nsplit;

  k_zero<<<dim3(1), dim3(64), 0, stream>>>(counts, probsum, lsq);
  k_gemm<<<dim3(NTOK / 64, nsplit), dim3(128), 0, stream>>>(x, Wm, part, ksz);
  k_reduce<<<dim3(4096), dim3(256), 0, stream>>>(part, out + O_LOGITS, nsplit);
  k_rowwise<<<dim3(64), dim3(256), 0, stream>>>(part, out, counts, probsum, lsq, flat);
  k_final<<<dim3(1), dim3(64), 0, stream>>>(counts, probsum, lsq, out, offs);
  k_dispatch<<<dim3(64), dim3(256), 0, stream>>>(flat, offs, out);
}

// Round 2
// 358.949 us; speedup vs baseline: 1.3390x; 1.3390x over previous
//
#include <hip/hip_runtime.h>
#include <hip/hip_bf16.h>
#include <math.h>

#define NTOK   16384
#define NEXP   64
#define HID    4096
#define KSEL   8
#define EPS    1.25e-4f

// d_out element offsets (f32 elements; int outputs stored as float values)
#define O_LOGITS 0u
#define O_PROBS  1048576u
#define O_TIDX   1179648u
#define O_GROUP  1310720u
#define O_IDX    1310784u
#define O_TPE    1441856u
#define O_LB     1441920u
#define O_ZL     1441921u

// ws byte offsets
#define W_CQ      0u          // 256 int: counts[q][e], q = row>>12
#define W_PROBSUM 1024u       // 64 float
#define W_LSQ     1280u       // 1 double
#define W_GCOUNT  1288u       // 1 int (flagged-row count)
#define W_OFFS2   2048u       // 256 int: offsets[e][q]
#define W_LIST    4096u       // 16384 int (flagged rows)
#define W_FLAT    69632u      // 131072 int (flat topk expert ids)
#define W_WT      1048576u    // 1 MB: W transposed [h][e] f32
#define W_PART    2097152u    // nsplit x 4 MB f32 partials
#define PART_STRIDE 1048576ull  // floats per split

__device__ __forceinline__ void gload16(const void* g, void* l) {
  __builtin_amdgcn_global_load_lds((const __attribute__((address_space(1))) unsigned int*)g,
                                   (__attribute__((address_space(3))) unsigned int*)l, 16, 0, 0);
}

// ---------------------------------------------------------------------------
__global__ void k_zero(int* cq, float* probsum, double* lsq, int* gcount) {
  int t = threadIdx.x;
  cq[t] = 0;
  if (t < 64) probsum[t] = 0.0f;
  if (t == 0) { lsq[0] = 0.0; gcount[0] = 0; }
}

// ---------------------------------------------------------------------------
// Transpose W [64][4096] -> Wt [4096][64] (1 MB, one-time per call)
__global__ __launch_bounds__(256) void k_wt(const float* __restrict__ w, float* __restrict__ wt) {
  __shared__ float tile[64][65];
  const int h0 = blockIdx.x * 64;
  const int tid = threadIdx.x;
#pragma unroll
  for (int r = 0; r < 16; ++r) {
    int li = r * 256 + tid;
    int e = li >> 6, h = li & 63;
    tile[e][h] = w[(size_t)e * HID + h0 + h];
  }
  __syncthreads();
#pragma unroll
  for (int r = 0; r < 16; ++r) {
    int li = r * 256 + tid;
    int h = li >> 6, e = li & 63;
    wt[(size_t)(h0 + h) * 64 + e] = tile[e][h];
  }
}

// ---------------------------------------------------------------------------
// f32 router GEMM. 64-row x 64-expert tile, split-K, 128 threads.
// Thread = 4 rows x 8 experts. global_load_lds staging, double-buffered,
// x-tile XOR-swizzled at 16B granularity for conflict-free b128 reads.
__global__ __launch_bounds__(128) void k_gemm(const float* __restrict__ x,
                                              const float* __restrict__ wt,
                                              float* __restrict__ part, int ksz) {
  __shared__ float xs[2][2048];   // [buf][row*32 + pslot*4 + c], 8 KB each
  __shared__ float wl[2][2048];   // [buf][hh*64 + e], 8 KB each
  const int t0   = blockIdx.x * 64;
  const int k0   = blockIdx.y * ksz;
  const int tid  = threadIdx.x;
  const int eg   = tid & 7;       // 8 experts
  const int rg   = tid >> 3;      // 4 rows, 0..15
  const int wave = tid >> 6;
  const int lane = tid & 63;

  auto stage = [&](int kb, int b) {
#pragma unroll
    for (int s = 0; s < 4; ++s) {            // x: 64 rows x 32 cols
      int brow = (wave * 4 + s) * 8;
      int row  = brow + (lane >> 3);
      int ls   = (lane & 7) ^ ((row >> 2) & 7);   // logical 16B slot
      gload16(x + (size_t)(t0 + row) * HID + kb + ls * 4, &xs[b][brow * 32]);
    }
#pragma unroll
    for (int s = 0; s < 4; ++s) {            // wt: 32 hh x 64 e, linear
      int bo = (wave * 4 + s) * 256;         // float offset of this 1KB
      int fo = bo + lane * 4;
      int hh = fo >> 6;
      int e4 = fo & 63;
      gload16(wt + (size_t)(kb + hh) * 64 + e4, &wl[b][bo]);
    }
  };

  float acc[4][8];
#pragma unroll
  for (int i = 0; i < 4; ++i)
#pragma unroll
    for (int j = 0; j < 8; ++j) acc[i][j] = 0.0f;

  const int nch = ksz >> 5;
  stage(k0, 0);
  __syncthreads();
  for (int c = 0; c < nch; ++c) {
    const int b = c & 1;
    if (c + 1 < nch) stage(k0 + (c + 1) * 32, b ^ 1);
#pragma unroll
    for (int h4 = 0; h4 < 8; ++h4) {
      float4 rx[4];
      const int ps = h4 ^ (rg & 7);
#pragma unroll
      for (int i = 0; i < 4; ++i)
        rx[i] = *(const float4*)&xs[b][(rg * 4 + i) * 32 + ps * 4];
#pragma unroll
      for (int l = 0; l < 4; ++l) {
        float4 wa = *(const float4*)&wl[b][(h4 * 4 + l) * 64 + eg * 8];
        float4 wb = *(const float4*)&wl[b][(h4 * 4 + l) * 64 + eg * 8 + 4];
#pragma unroll
        for (int i = 0; i < 4; ++i) {
          float xv = (&rx[i].x)[l];
          acc[i][0] = fmaf(xv, wa.x, acc[i][0]);
          acc[i][1] = fmaf(xv, wa.y, acc[i][1]);
          acc[i][2] = fmaf(xv, wa.z, acc[i][2]);
          acc[i][3] = fmaf(xv, wa.w, acc[i][3]);
          acc[i][4] = fmaf(xv, wb.x, acc[i][4]);
          acc[i][5] = fmaf(xv, wb.y, acc[i][5]);
          acc[i][6] = fmaf(xv, wb.z, acc[i][6]);
          acc[i][7] = fmaf(xv, wb.w, acc[i][7]);
        }
      }
    }
    __syncthreads();
  }

  float* p = part + (size_t)blockIdx.y * PART_STRIDE + (size_t)t0 * 64;
#pragma unroll
  for (int i = 0; i < 4; ++i) {
    float4 v0 = make_float4(acc[i][0], acc[i][1], acc[i][2], acc[i][3]);
    float4 v1 = make_float4(acc[i][4], acc[i][5], acc[i][6], acc[i][7]);
    *(float4*)&p[(rg * 4 + i) * 64 + eg * 8]     = v0;
    *(float4*)&p[(rg * 4 + i) * 64 + eg * 8 + 4] = v1;
  }
}

// ---------------------------------------------------------------------------
__global__ __launch_bounds__(256) void k_reduce(const float* __restrict__ part,
                                                float* __restrict__ out_logits, int nsplit) {
  unsigned i4 = blockIdx.x * 256u + threadIdx.x;   // 1024 x 256 = 262144 float4s
  const float4* p4 = (const float4*)part;
  float4 v = p4[i4];
  for (int s = 1; s < nsplit; ++s) {
    float4 a = p4[(size_t)s * (PART_STRIDE / 4) + i4];
    v.x += a.x; v.y += a.y; v.z += a.z; v.w += a.w;
  }
  ((float4*)out_logits)[i4] = v;
}

// ---------------------------------------------------------------------------
// Per-row: top-9 on clipped f32, flag near-ties, top-8 softmax + hist for
// clean rows, losses for all rows. 256 blocks x 64 threads (1 wave).
__global__ __launch_bounds__(64) void k_rowwise(const float* __restrict__ lg,
                                                float* __restrict__ out,
                                                int* __restrict__ cq,
                                                float* __restrict__ probsum,
                                                double* __restrict__ lsq,
                                                int* __restrict__ flat,
                                                int* __restrict__ gcount,
                                                int* __restrict__ list) {
  __shared__ int hist[64];
  const int tid = threadIdx.x;
  const unsigned t = blockIdx.x * 64u + tid;
  const int q = blockIdx.x >> 6;
  hist[tid] = 0;
  __syncthreads();

  float lv[64];
  const float4* lp = (const float4*)(lg + (size_t)t * 64);
#pragma unroll
  for (int k = 0; k < 16; ++k) {
    float4 f = lp[k];
    lv[k * 4] = f.x; lv[k * 4 + 1] = f.y; lv[k * 4 + 2] = f.z; lv[k * 4 + 3] = f.w;
  }

  float val[9]; int idx[9];
#pragma unroll
  for (int j = 0; j < 9; ++j) { val[j] = -3.0e38f; idx[j] = 0; }
  float rm = -3.0e38f;
  bool flag = false;
#pragma unroll
  for (int e = 0; e < 64; ++e) {
    float v = lv[e];
    rm = fmaxf(rm, v);
    flag = flag || (fabsf(fabsf(v) - 2.0f) < EPS);
    float c = fminf(fmaxf(v, -2.0f), 2.0f);
    int id = e;
#pragma unroll
    for (int j = 0; j < 9; ++j) {
      bool sw = c > val[j];
      float tv = sw ? val[j] : c; int ti = sw ? idx[j] : id;
      val[j] = sw ? c : val[j];   idx[j] = sw ? id : idx[j];
      c = tv; id = ti;
    }
  }
#pragma unroll
  for (int j = 0; j < 8; ++j) {
    float gap = val[j] - val[j + 1];
    bool bothclip = (val[j] == val[j + 1]) && (fabsf(val[j]) == 2.0f);
    flag = flag || (gap < EPS && !bothclip);
  }

  if (!flag) {
    float m = val[0], pe[8], sum = 0.0f;
#pragma unroll
    for (int j = 0; j < 8; ++j) { pe[j] = expf(val[j] - m); sum += pe[j]; }
    float inv = 1.0f / sum;
#pragma unroll
    for (int j = 0; j < 8; ++j) {
      out[O_PROBS + (size_t)t * 8 + j] = pe[j] * inv;
      out[O_TIDX  + (size_t)t * 8 + j] = (float)idx[j];
      flat[(size_t)t * 8 + j] = idx[j];
      atomicAdd(&hist[idx[j]], 1);
    }
  } else {
    int sl = atomicAdd(gcount, 1);
    list[sl] = (int)t;
  }

  // losses from f32 logits (thresholds ~2%, f32 is plenty) — all rows
  float se = 0.0f;
#pragma unroll
  for (int e = 0; e < 64; ++e) se += expf(lv[e] - rm);
  float inv = 1.0f / se;
#pragma unroll
  for (int e = 0; e < 64; ++e) {
    float p = expf(lv[e] - rm) * inv;
#pragma unroll
    for (int o = 32; o > 0; o >>= 1) p += __shfl_down(p, o);
    if (tid == 0) atomicAdd(&probsum[e], p);
  }
  float lse = rm + logf(se);
  float l2 = lse * lse;
#pragma unroll
  for (int o = 32; o > 0; o >>= 1) l2 += __shfl_down(l2, o);
  if (tid == 0) atomicAdd(lsq, (double)l2);

  __syncthreads();
  atomicAdd(&cq[q * 64 + tid], hist[tid]);
}

// ---------------------------------------------------------------------------
// f64 repair of flagged rows: recompute all 64 dots exactly, redo top-8.
__global__ __launch_bounds__(256) void k_repair(const float* __restrict__ x,
                                                const float* __restrict__ w,
                                                const int* __restrict__ list,
                                                const int* __restrict__ gcount,
                                                float* __restrict__ out,
                                                int* __restrict__ cq,
                                                int* __restrict__ flat) {
  __shared__ double sh[4][64];
  __shared__ double tot[64];
  const int tid = threadIdx.x;
  const int wave = tid >> 6, lane = tid & 63;
  const int n = *gcount;
  for (int i = blockIdx.x; i < n; i += gridDim.x) {
    const int row = list[i];
    const float* xr = x + (size_t)row * HID;
    const float* wr = w + (size_t)lane * HID;
    double p = 0.0;
    const int kb = wave * 1024;
    for (int k = kb; k < kb + 1024; k += 4) {
      float4 xv = *(const float4*)&xr[k];
      float4 wv = *(const float4*)&wr[k];
      p = fma((double)xv.x, (double)wv.x, p);
      p = fma((double)xv.y, (double)wv.y, p);
      p = fma((double)xv.z, (double)wv.z, p);
      p = fma((double)xv.w, (double)wv.w, p);
    }
    sh[wave][lane] = p;
    __syncthreads();
    if (wave == 0) tot[lane] = sh[0][lane] + sh[1][lane] + sh[2][lane] + sh[3][lane];
    __syncthreads();
    if (tid == 0) {
      double val[8]; int idx[8];
#pragma unroll
      for (int j = 0; j < 8; ++j) { val[j] = -1.0e300; idx[j] = 0; }
      for (int e = 0; e < 64; ++e) {
        double c = fmin(fmax(tot[e], -2.0), 2.0);
        int id = e;
#pragma unroll
        for (int j = 0; j < 8; ++j) {
          bool sw = c > val[j];
          double tv = sw ? val[j] : c; int ti = sw ? idx[j] : id;
          val[j] = sw ? c : val[j];    idx[j] = sw ? id : idx[j];
          c = tv; id = ti;
        }
      }
      float m = (float)val[0], pe[8], sum = 0.0f;
#pragma unroll
      for (int j = 0; j < 8; ++j) { pe[j] = expf((float)val[j] - m); sum += pe[j]; }
      float inv = 1.0f / sum;
      const int q = row >> 12;
#pragma unroll
      for (int j = 0; j < 8; ++j) {
        out[O_PROBS + (size_t)row * 8 + j] = pe[j] * inv;
        out[O_TIDX  + (size_t)row * 8 + j] = (float)idx[j];
        flat[(size_t)row * 8 + j] = idx[j];
        atomicAdd(&cq[q * 64 + idx[j]], 1);
      }
    }
    __syncthreads();
  }
}

// ---------------------------------------------------------------------------
__global__ void k_final(const int* __restrict__ cq, const float* __restrict__ probsum,
                        const double* __restrict__ lsq, float* __restrict__ out,
                        int* __restrict__ offs2) {
  __shared__ int ctot[64];
  const int e = threadIdx.x;
  int tpe = cq[e] + cq[64 + e] + cq[128 + e] + cq[192 + e];
  ctot[e] = tpe;
  __syncthreads();
  int incl = 0;
  for (int i = 0; i <= e; ++i) incl += ctot[i];
  out[O_TPE + e]   = (float)tpe;
  out[O_GROUP + e] = (float)incl;
  int o = incl - tpe;
#pragma unroll
  for (int q = 0; q < 4; ++q) { offs2[e * 4 + q] = o; o += cq[q * 64 + e]; }
  float term = ((float)tpe / 131072.0f) * (probsum[e] / 16384.0f) * 64.0f;
#pragma unroll
  for (int o2 = 32; o2 > 0; o2 >>= 1) term += __shfl_down(term, o2);
  if (e == 0) {
    out[O_LB] = term;
    out[O_ZL] = (float)(lsq[0] / 16384.0);
  }
}

// ---------------------------------------------------------------------------
// Stable counting-sort scatter, split 4x by row-quarter: 256 blocks.
__global__ __launch_bounds__(256) void k_dispatch(const int* __restrict__ flat,
                                                  const int* __restrict__ offs2,
                                                  float* __restrict__ out) {
  __shared__ int wcs[4];
  const int e = blockIdx.x >> 2;
  const int q = blockIdx.x & 3;
  const int tid = threadIdx.x;
  const int lane = tid & 63;
  const int wv = tid >> 6;
  int base = offs2[e * 4 + q];
  const int seg0 = q * 32768;
  for (int c0 = 0; c0 < 32768; c0 += 2048) {
    const int j0 = seg0 + c0 + tid * 8;
    const int4* f4 = reinterpret_cast<const int4*>(flat + j0);
    int4 a = f4[0], b = f4[1];
    int v[8] = {a.x, a.y, a.z, a.w, b.x, b.y, b.z, b.w};
    int mcnt = 0;
#pragma unroll
    for (int k = 0; k < 8; ++k) mcnt += (v[k] == e) ? 1 : 0;
    int sc = mcnt;
#pragma unroll
    for (int o = 1; o < 64; o <<= 1) {
      int nn = __shfl_up(sc, o);
      if (lane >= o) sc += nn;
    }
    int excl = sc - mcnt;
    if (lane == 63) wcs[wv] = sc;
    __syncthreads();
    int woff = 0, tot = 0;
#pragma unroll
    for (int i = 0; i < 4; ++i) { int ci = wcs[i]; woff += (i < wv) ? ci : 0; tot += ci; }
    int pos = base + woff + excl;
#pragma unroll
    for (int k = 0; k < 8; ++k) {
      if (v[k] == e) { out[O_IDX + pos] = (float)(j0 + k); pos++; }
    }
    base += tot;
    __syncthreads();
  }
}

// ---------------------------------------------------------------------------
extern "C" void kernel_launch(void* const* d_in, const int* in_sizes, int n_in,
                              void* d_out, int out_size, void* d_ws, size_t ws_size,
                              hipStream_t stream) {
  (void)in_sizes; (void)n_in; (void)out_size;
  const float* x  = (const float*)d_in[0];
  const float* Wm = (const float*)d_in[1];
  float* out = (float*)d_out;
  char*  ws  = (char*)d_ws;

  int*    cq      = (int*)(ws + W_CQ);
  float*  probsum = (float*)(ws + W_PROBSUM);
  double* lsq     = (double*)(ws + W_LSQ);
  int*    gcount  = (int*)(ws + W_GCOUNT);
  int*    offs2   = (int*)(ws + W_OFFS2);
  int*    list    = (int*)(ws + W_LIST);
  int*    flat    = (int*)(ws + W_FLAT);
  float*  wt      = (float*)(ws + W_WT);
  float*  part    = (float*)(ws + W_PART);

  int nsplit = 1;
  if (ws_size >= (size_t)W_PART + 4ull * PART_STRIDE * 4ull) nsplit = 4;
  else if (ws_size >= (size_t)W_PART + 2ull * PART_STRIDE * 4ull) nsplit = 2;
  const int ksz = HID / nsplit;

  k_zero    <<<dim3(1),    dim3(256), 0, stream>>>(cq, probsum, lsq, gcount);
  k_wt      <<<dim3(64),   dim3(256), 0, stream>>>(Wm, wt);
  k_gemm    <<<dim3(NTOK / 64, nsplit), dim3(128), 0, stream>>>(x, wt, part, ksz);
  k_reduce  <<<dim3(1024), dim3(256), 0, stream>>>(part, out + O_LOGITS, nsplit);
  k_rowwise <<<dim3(256),  dim3(64),  0, stream>>>(out + O_LOGITS, out, cq, probsum, lsq, flat, gcount, list);
  k_repair  <<<dim3(256),  dim3(256), 0, stream>>>(x, Wm, list, gcount, out, cq, flat);
  k_final   <<<dim3(1),    dim3(64),  0, stream>>>(cq, probsum, lsq, out, offs2);
  k_dispatch<<<dim3(256),  dim3(256), 0, stream>>>(flat, offs2, out);
}

// Round 3
// 187.255 us; speedup vs baseline: 2.5667x; 1.9169x over previous
//
#include <hip/hip_runtime.h>
#include <hip/hip_bf16.h>
#include <math.h>

#define NTOK   16384
#define NEXP   64
#define HID    4096
#define KSEL   8
#define EPS    7.5e-5f

typedef __attribute__((ext_vector_type(8))) short short8;
typedef __attribute__((ext_vector_type(4))) float f32x4;

// d_out element offsets (f32 elements; int outputs stored as float values)
#define O_LOGITS 0u
#define O_PROBS  1048576u
#define O_TIDX   1179648u
#define O_GROUP  1310720u
#define O_IDX    1310784u
#define O_TPE    1441856u
#define O_LB     1441920u
#define O_ZL     1441921u

// ws byte offsets
#define W_CQ      0u          // 512 int: counts[q][e], q = row>>11 (8 quarters)
#define W_GCOUNT  2048u       // 1 int
#define W_OFFS2   4096u       // 512 int: offsets[e][q]
#define W_LSQP    8192u       // 256 f32: per-block z-loss partials
#define W_LIST    16384u      // 16384 int (flagged rows)
#define W_PSUM    81920u      // 256*64 f32: per-block probsum partials
#define W_FLAT    147456u     // 131072 int
#define W_WF      1048576u    // 1 MB: W packed as MFMA B-frags, bf16 hi/lo
#define W_PART    2097152u    // nsplit x 4 MB f32 partials
#define PART_STRIDE 1048576ull

// round-to-nearest-even f32 -> bf16 bits
__device__ __forceinline__ unsigned short f2bf(float f) {
  unsigned u = __float_as_uint(f);
  return (unsigned short)((u + 0x7fffu + ((u >> 16) & 1u)) >> 16);
}

// ---------------------------------------------------------------------------
__global__ void k_zero(int* cq, int* gcount) {
  cq[threadIdx.x] = 0;
  if (threadIdx.x == 0) gcount[0] = 0;
}

// ---------------------------------------------------------------------------
// Pack W [64][4096] f32 into MFMA B-fragments, bf16 hi/lo.
// B[k][n] = W[n][k].  frag(kk, nb, hl): lane holds 8 bf16, j ->
// B[kk*32 + (lane>>4)*8 + j][nb*16 + (lane&15)].
// Layout: wf[ ((kk*4 + nb)*2 + hl)*64 + lane ] as short8.
__global__ __launch_bounds__(256) void k_wf(const float* __restrict__ w,
                                            short8* __restrict__ wf) {
  const int kk   = blockIdx.x;           // 128
  const int nb   = threadIdx.x >> 6;     // 4
  const int lane = threadIdx.x & 63;
  const int n    = nb * 16 + (lane & 15);
  const int kb   = kk * 32 + (lane >> 4) * 8;
  const float4* wp = (const float4*)(w + (size_t)n * HID + kb);
  float4 f0 = wp[0], f1 = wp[1];
  float fv[8] = {f0.x, f0.y, f0.z, f0.w, f1.x, f1.y, f1.z, f1.w};
  short8 hi, lo;
#pragma unroll
  for (int j = 0; j < 8; ++j) {
    unsigned short h = f2bf(fv[j]);
    hi[j] = (short)h;
    float r = fv[j] - __uint_as_float((unsigned)h << 16);
    lo[j] = (short)f2bf(r);
  }
  size_t base = ((size_t)(kk * 4 + nb) * 2) * 64 + lane;
  wf[base] = hi;
  wf[base + 64] = lo;
}

// ---------------------------------------------------------------------------
// MFMA router GEMM: 4-term bf16 Ozaki split, f32 accumulate.
// Block 256 thr = 4 waves; wave = 16 rows x 64 experts (4 N-frags).
// No LDS, no barriers: x A-frags loaded per-lane from HBM, W B-frags from L2.
__global__ __launch_bounds__(256, 2) void k_gemm(const float* __restrict__ x,
                                                 const short8* __restrict__ wf,
                                                 float* __restrict__ part, int ksz) {
  const int tid  = threadIdx.x;
  const int wv   = tid >> 6;
  const int lane = tid & 63;
  const int t0   = blockIdx.x * 64;
  const int k0   = blockIdx.y * ksz;
  const int row  = t0 + wv * 16 + (lane & 15);

  const float* xp = x + (size_t)row * HID + k0 + (lane >> 4) * 8;
  const short8* wp = wf + ((size_t)(k0 >> 5) * 4 * 2) * 64 + lane;

  f32x4 acc[4] = {{0,0,0,0},{0,0,0,0},{0,0,0,0},{0,0,0,0}};
  const int nkk = ksz >> 5;

#pragma unroll 2
  for (int kk = 0; kk < nkk; ++kk) {
    const float4* xq = (const float4*)(xp + kk * 32);
    float4 f0 = xq[0], f1 = xq[1];
    const short8* wq = wp + (size_t)kk * 8 * 64;
    short8 bh0 = wq[0],   bl0 = wq[64];
    short8 bh1 = wq[128], bl1 = wq[192];
    short8 bh2 = wq[256], bl2 = wq[320];
    short8 bh3 = wq[384], bl3 = wq[448];

    float fv[8] = {f0.x, f0.y, f0.z, f0.w, f1.x, f1.y, f1.z, f1.w};
    short8 ah, al;
#pragma unroll
    for (int j = 0; j < 8; ++j) {
      unsigned short h = f2bf(fv[j]);
      ah[j] = (short)h;
      float r = fv[j] - __uint_as_float((unsigned)h << 16);
      al[j] = (short)f2bf(r);
    }
    acc[0] = __builtin_amdgcn_mfma_f32_16x16x32_bf16(al, bl0, acc[0], 0, 0, 0);
    acc[0] = __builtin_amdgcn_mfma_f32_16x16x32_bf16(ah, bl0, acc[0], 0, 0, 0);
    acc[0] = __builtin_amdgcn_mfma_f32_16x16x32_bf16(al, bh0, acc[0], 0, 0, 0);
    acc[0] = __builtin_amdgcn_mfma_f32_16x16x32_bf16(ah, bh0, acc[0], 0, 0, 0);
    acc[1] = __builtin_amdgcn_mfma_f32_16x16x32_bf16(al, bl1, acc[1], 0, 0, 0);
    acc[1] = __builtin_amdgcn_mfma_f32_16x16x32_bf16(ah, bl1, acc[1], 0, 0, 0);
    acc[1] = __builtin_amdgcn_mfma_f32_16x16x32_bf16(al, bh1, acc[1], 0, 0, 0);
    acc[1] = __builtin_amdgcn_mfma_f32_16x16x32_bf16(ah, bh1, acc[1], 0, 0, 0);
    acc[2] = __builtin_amdgcn_mfma_f32_16x16x32_bf16(al, bl2, acc[2], 0, 0, 0);
    acc[2] = __builtin_amdgcn_mfma_f32_16x16x32_bf16(ah, bl2, acc[2], 0, 0, 0);
    acc[2] = __builtin_amdgcn_mfma_f32_16x16x32_bf16(al, bh2, acc[2], 0, 0, 0);
    acc[2] = __builtin_amdgcn_mfma_f32_16x16x32_bf16(ah, bh2, acc[2], 0, 0, 0);
    acc[3] = __builtin_amdgcn_mfma_f32_16x16x32_bf16(al, bl3, acc[3], 0, 0, 0);
    acc[3] = __builtin_amdgcn_mfma_f32_16x16x32_bf16(ah, bl3, acc[3], 0, 0, 0);
    acc[3] = __builtin_amdgcn_mfma_f32_16x16x32_bf16(al, bh3, acc[3], 0, 0, 0);
    acc[3] = __builtin_amdgcn_mfma_f32_16x16x32_bf16(ah, bh3, acc[3], 0, 0, 0);
  }

  // D[m = (lane>>4)*4 + reg][n = nb*16 + (lane&15)]
  float* p = part + (size_t)blockIdx.y * PART_STRIDE;
  const int mrow = t0 + wv * 16 + (lane >> 4) * 4;
  const int col  = lane & 15;
#pragma unroll
  for (int nb = 0; nb < 4; ++nb)
#pragma unroll
    for (int r = 0; r < 4; ++r)
      p[(size_t)(mrow + r) * 64 + nb * 16 + col] = acc[nb][r];
}

// ---------------------------------------------------------------------------
__global__ __launch_bounds__(256) void k_reduce(const float* __restrict__ part,
                                                float* __restrict__ out_logits, int nsplit) {
  unsigned i4 = blockIdx.x * 256u + threadIdx.x;   // 1024 x 256 float4s
  const float4* p4 = (const float4*)part;
  float4 v = p4[i4];
  for (int s = 1; s < nsplit; ++s) {
    float4 a = p4[(size_t)s * (PART_STRIDE / 4) + i4];
    v.x += a.x; v.y += a.y; v.z += a.z; v.w += a.w;
  }
  ((float4*)out_logits)[i4] = v;
}

// ---------------------------------------------------------------------------
// Per-64-row block: LDS-tiled. Phase A (thread=row): top-9 + flag + top-8
// softmax + hist + z-loss, store exp() back into tile. Phase B (thread=col):
// column-sum of softmax probs -> deterministic per-block partials.
__global__ __launch_bounds__(64) void k_rowwise(const float* __restrict__ lg,
                                                float* __restrict__ out,
                                                int* __restrict__ cq,
                                                float* __restrict__ psum_part,
                                                float* __restrict__ lsq_part,
                                                int* __restrict__ flat,
                                                int* __restrict__ gcount,
                                                int* __restrict__ list) {
  __shared__ float tile[64][68];
  __shared__ float invv[64];
  __shared__ int hist[64];
  const int tid = threadIdx.x;
  const unsigned t = blockIdx.x * 64u + tid;
  const int q = blockIdx.x >> 5;
  hist[tid] = 0;

  // coop load 64x64 tile (coalesced)
  const float4* src = (const float4*)(lg + (size_t)blockIdx.x * 64 * 64);
#pragma unroll
  for (int c = 0; c < 16; ++c) {
    int idx = c * 64 + tid;              // float4 index
    int rrow = idx >> 4, col4 = idx & 15;
    *(float4*)&tile[rrow][col4 * 4] = src[idx];
  }
  __syncthreads();

  float lv[64];
#pragma unroll
  for (int c = 0; c < 16; ++c) {
    float4 f = *(const float4*)&tile[tid][c * 4];
    lv[c * 4] = f.x; lv[c * 4 + 1] = f.y; lv[c * 4 + 2] = f.z; lv[c * 4 + 3] = f.w;
  }

  // top-9 stable insertion on clipped keys + flag near-ties
  float val[9]; int idx[9];
#pragma unroll
  for (int j = 0; j < 9; ++j) { val[j] = -3.0e38f; idx[j] = 0; }
  float rm = -3.0e38f;
  bool flag = false;
#pragma unroll
  for (int e = 0; e < 64; ++e) {
    float v = lv[e];
    rm = fmaxf(rm, v);
    flag = flag || (fabsf(fabsf(v) - 2.0f) < EPS);
    float c = fminf(fmaxf(v, -2.0f), 2.0f);
    int id = e;
#pragma unroll
    for (int j = 0; j < 9; ++j) {
      bool sw = c > val[j];
      float tv = sw ? val[j] : c; int ti = sw ? idx[j] : id;
      val[j] = sw ? c : val[j];   idx[j] = sw ? id : idx[j];
      c = tv; id = ti;
    }
  }
#pragma unroll
  for (int j = 0; j < 8; ++j) {
    float gap = val[j] - val[j + 1];
    bool bothclip = (val[j] == val[j + 1]) && (fabsf(val[j]) == 2.0f);
    flag = flag || (gap < EPS && !bothclip);
  }

  if (!flag) {
    float m = val[0], pe[8], sum = 0.0f;
#pragma unroll
    for (int j = 0; j < 8; ++j) { pe[j] = expf(val[j] - m); sum += pe[j]; }
    float inv = 1.0f / sum;
#pragma unroll
    for (int j = 0; j < 8; ++j) {
      out[O_PROBS + (size_t)t * 8 + j] = pe[j] * inv;
      out[O_TIDX  + (size_t)t * 8 + j] = (float)idx[j];
      flat[(size_t)t * 8 + j] = idx[j];
      atomicAdd(&hist[idx[j]], 1);
    }
  } else {
    int sl = atomicAdd(gcount, 1);
    list[sl] = (int)t;
  }

  // full softmax denom; store exp() back into tile for phase B
  float se = 0.0f;
#pragma unroll
  for (int e = 0; e < 64; ++e) {
    float pv = expf(lv[e] - rm);
    tile[tid][e] = pv;
    se += pv;
  }
  invv[tid] = 1.0f / se;

  float lse = rm + logf(se);
  float l2 = lse * lse;
#pragma unroll
  for (int o = 32; o > 0; o >>= 1) l2 += __shfl_down(l2, o);
  if (tid == 0) lsq_part[blockIdx.x] = l2;

  __syncthreads();
  // phase B: thread = expert column
  float s = 0.0f;
#pragma unroll
  for (int r = 0; r < 64; ++r) s += tile[r][tid] * invv[r];
  psum_part[(size_t)blockIdx.x * 64 + tid] = s;

  atomicAdd(&cq[q * 64 + tid], hist[tid]);
}

// ---------------------------------------------------------------------------
// Exact f64 repair of flagged rows (4 independent accumulator chains).
__global__ __launch_bounds__(256) void k_repair(const float* __restrict__ x,
                                                const float* __restrict__ w,
                                                const int* __restrict__ list,
                                                const int* __restrict__ gcount,
                                                float* __restrict__ out,
                                                int* __restrict__ cq,
                                                int* __restrict__ flat) {
  __shared__ double sh[4][64];
  __shared__ double tot[64];
  const int tid = threadIdx.x;
  const int wave = tid >> 6, lane = tid & 63;
  const int n = *gcount;
  for (int i = blockIdx.x; i < n; i += gridDim.x) {
    const int row = list[i];
    const float* xr = x + (size_t)row * HID;
    const float* wr = w + (size_t)lane * HID;
    double p0 = 0.0, p1 = 0.0, p2 = 0.0, p3 = 0.0;
    const int kb = wave * 1024;
    for (int k = kb; k < kb + 1024; k += 4) {
      float4 xv = *(const float4*)&xr[k];
      float4 wv = *(const float4*)&wr[k];
      p0 = fma((double)xv.x, (double)wv.x, p0);
      p1 = fma((double)xv.y, (double)wv.y, p1);
      p2 = fma((double)xv.z, (double)wv.z, p2);
      p3 = fma((double)xv.w, (double)wv.w, p3);
    }
    sh[wave][lane] = (p0 + p1) + (p2 + p3);
    __syncthreads();
    if (wave == 0) tot[lane] = (sh[0][lane] + sh[1][lane]) + (sh[2][lane] + sh[3][lane]);
    __syncthreads();
    if (tid == 0) {
      double val[8]; int idx[8];
#pragma unroll
      for (int j = 0; j < 8; ++j) { val[j] = -1.0e300; idx[j] = 0; }
      for (int e = 0; e < 64; ++e) {
        double c = fmin(fmax(tot[e], -2.0), 2.0);
        int id = e;
#pragma unroll
        for (int j = 0; j < 8; ++j) {
          bool sw = c > val[j];
          double tv = sw ? val[j] : c; int ti = sw ? idx[j] : id;
          val[j] = sw ? c : val[j];    idx[j] = sw ? id : idx[j];
          c = tv; id = ti;
        }
      }
      float m = (float)val[0], pe[8], sum = 0.0f;
#pragma unroll
      for (int j = 0; j < 8; ++j) { pe[j] = expf((float)val[j] - m); sum += pe[j]; }
      float inv = 1.0f / sum;
      const int q = row >> 11;
#pragma unroll
      for (int j = 0; j < 8; ++j) {
        out[O_PROBS + (size_t)row * 8 + j] = pe[j] * inv;
        out[O_TIDX  + (size_t)row * 8 + j] = (float)idx[j];
        flat[(size_t)row * 8 + j] = idx[j];
        atomicAdd(&cq[q * 64 + idx[j]], 1);
      }
    }
    __syncthreads();
  }
}

// ---------------------------------------------------------------------------
__global__ void k_final(const int* __restrict__ cq, const float* __restrict__ psum_part,
                        const float* __restrict__ lsq_part, float* __restrict__ out,
                        int* __restrict__ offs2) {
  __shared__ int ctot[64];
  const int e = threadIdx.x;   // 64 threads
  int tpe = 0;
#pragma unroll
  for (int q = 0; q < 8; ++q) tpe += cq[q * 64 + e];
  ctot[e] = tpe;
  __syncthreads();
  int incl = 0;
  for (int i = 0; i <= e; ++i) incl += ctot[i];
  out[O_TPE + e]   = (float)tpe;
  out[O_GROUP + e] = (float)incl;
  int o = incl - tpe;
#pragma unroll
  for (int q = 0; q < 8; ++q) { offs2[e * 8 + q] = o; o += cq[q * 64 + e]; }

  float ps = 0.0f;
  for (int b = 0; b < 256; ++b) ps += psum_part[b * 64 + e];
  float term = ((float)tpe / 131072.0f) * (ps / 16384.0f) * 64.0f;
#pragma unroll
  for (int o2 = 32; o2 > 0; o2 >>= 1) term += __shfl_down(term, o2);

  float zs = lsq_part[e * 4] + lsq_part[e * 4 + 1] + lsq_part[e * 4 + 2] + lsq_part[e * 4 + 3];
#pragma unroll
  for (int o2 = 32; o2 > 0; o2 >>= 1) zs += __shfl_down(zs, o2);

  if (e == 0) {
    out[O_LB] = term;
    out[O_ZL] = zs / 16384.0f;
  }
}

// ---------------------------------------------------------------------------
// Stable counting-sort scatter, split 8x by row-eighth: 512 blocks.
__global__ __launch_bounds__(256) void k_dispatch(const int* __restrict__ flat,
                                                  const int* __restrict__ offs2,
                                                  float* __restrict__ out) {
  __shared__ int wcs[4];
  const int e = blockIdx.x >> 3;
  const int q = blockIdx.x & 7;
  const int tid = threadIdx.x;
  const int lane = tid & 63;
  const int wv = tid >> 6;
  int base = offs2[e * 8 + q];
  const int seg0 = q * 16384;
  for (int c0 = 0; c0 < 16384; c0 += 2048) {
    const int j0 = seg0 + c0 + tid * 8;
    const int4* f4 = reinterpret_cast<const int4*>(flat + j0);
    int4 a = f4[0], b = f4[1];
    int v[8] = {a.x, a.y, a.z, a.w, b.x, b.y, b.z, b.w};
    int mcnt = 0;
#pragma unroll
    for (int k = 0; k < 8; ++k) mcnt += (v[k] == e) ? 1 : 0;
    int sc = mcnt;
#pragma unroll
    for (int o = 1; o < 64; o <<= 1) {
      int nn = __shfl_up(sc, o);
      if (lane >= o) sc += nn;
    }
    int excl = sc - mcnt;
    if (lane == 63) wcs[wv] = sc;
    __syncthreads();
    int woff = 0, tot = 0;
#pragma unroll
    for (int i = 0; i < 4; ++i) { int ci = wcs[i]; woff += (i < wv) ? ci : 0; tot += ci; }
    int pos = base + woff + excl;
#pragma unroll
    for (int k = 0; k < 8; ++k) {
      if (v[k] == e) { out[O_IDX + pos] = (float)(j0 + k); pos++; }
    }
    base += tot;
    __syncthreads();
  }
}

// ---------------------------------------------------------------------------
extern "C" void kernel_launch(void* const* d_in, const int* in_sizes, int n_in,
                              void* d_out, int out_size, void* d_ws, size_t ws_size,
                              hipStream_t stream) {
  (void)in_sizes; (void)n_in; (void)out_size;
  const float* x  = (const float*)d_in[0];
  const float* Wm = (const float*)d_in[1];
  float* out = (float*)d_out;
  char*  ws  = (char*)d_ws;

  int*    cq      = (int*)(ws + W_CQ);
  int*    gcount  = (int*)(ws + W_GCOUNT);
  int*    offs2   = (int*)(ws + W_OFFS2);
  float*  lsqp    = (float*)(ws + W_LSQP);
  int*    list    = (int*)(ws + W_LIST);
  float*  psump   = (float*)(ws + W_PSUM);
  int*    flat    = (int*)(ws + W_FLAT);
  short8* wf      = (short8*)(ws + W_WF);
  float*  part    = (float*)(ws + W_PART);

  int nsplit = 1;
  if (ws_size >= (size_t)W_PART + 4ull * PART_STRIDE * 4ull) nsplit = 4;
  else if (ws_size >= (size_t)W_PART + 2ull * PART_STRIDE * 4ull) nsplit = 2;
  const int ksz = HID / nsplit;

  k_zero    <<<dim3(1),    dim3(512), 0, stream>>>(cq, gcount);
  k_wf      <<<dim3(128),  dim3(256), 0, stream>>>(Wm, wf);
  k_gemm    <<<dim3(NTOK / 64, nsplit), dim3(256), 0, stream>>>(x, wf, part, ksz);
  k_reduce  <<<dim3(1024), dim3(256), 0, stream>>>(part, out + O_LOGITS, nsplit);
  k_rowwise <<<dim3(256),  dim3(64),  0, stream>>>(out + O_LOGITS, out, cq, psump, lsqp, flat, gcount, list);
  k_repair  <<<dim3(256),  dim3(256), 0, stream>>>(x, Wm, list, gcount, out, cq, flat);
  k_final   <<<dim3(1),    dim3(64),  0, stream>>>(cq, psump, lsqp, out, offs2);
  k_dispatch<<<dim3(512),  dim3(256), 0, stream>>>(flat, offs2, out);
}